// Round 6
// baseline (647.269 us; speedup 1.0000x reference)
//
#include <hip/hip_runtime.h>
#include <math.h>

#define BB    2
#define NN    2048
#define CDIM  1024
#define HEADS 16
#define HDIM  64
#define MLPD  4096
#define MODC  6144
#define EPSV  1e-5f
#define LOG2E 1.4426950408889634f

typedef __attribute__((ext_vector_type(8))) short s8v;     // 8 bf16 (4 VGPRs)
typedef __attribute__((ext_vector_type(4))) float f4v;     // MFMA C/D

__device__ inline unsigned short f2bf(float f) {
  union { float f; unsigned u; } v; v.f = f;
  unsigned r = v.u + 0x7FFFu + ((v.u >> 16) & 1u);   // RNE
  return (unsigned short)(r >> 16);
}
__device__ inline float bf2f(unsigned short h) {
  union { unsigned u; float f; } v; v.u = ((unsigned)h) << 16;
  return v.f;
}

// ---------------------------------------------------------------------------
// K1: mod = silu(t_emb) @ ada_W + ada_b        (B x 6144)
// ---------------------------------------------------------------------------
__global__ __launch_bounds__(256) void mod_kernel(
    const float* __restrict__ t_emb, const float* __restrict__ ada_W,
    const float* __restrict__ ada_b, float* __restrict__ mod) {
  int b = blockIdx.y;
  int j = blockIdx.x * 256 + threadIdx.x;
  __shared__ float st[CDIM];
  for (int i = threadIdx.x; i < CDIM; i += 256) {
    float v = t_emb[b * CDIM + i];
    st[i] = v / (1.0f + expf(-v));
  }
  __syncthreads();
  float acc = ada_b[j];
  for (int i = 0; i < CDIM; ++i) acc += st[i] * ada_W[(size_t)i * MODC + j];
  mod[b * MODC + j] = acc;
}

// ---------------------------------------------------------------------------
// K2: LN + adaLN modulation, bf16 output
// ---------------------------------------------------------------------------
__device__ inline float wave_sum64(float v) {
  for (int o = 32; o > 0; o >>= 1) v += __shfl_down(v, o, 64);
  return v;
}

__global__ __launch_bounds__(256) void ln_mod_bf16(
    const float* __restrict__ x, const float* __restrict__ g,
    const float* __restrict__ bta, const float* __restrict__ mod,
    int shift_off, int scale_off, unsigned short* __restrict__ out) {
  int r = blockIdx.x;
  int b = r / NN;
  int t = threadIdx.x;
  const float* xr = x + (size_t)r * CDIM;
  float4 xv = ((const float4*)xr)[t];
  float s  = xv.x + xv.y + xv.z + xv.w;
  float s2 = xv.x*xv.x + xv.y*xv.y + xv.z*xv.z + xv.w*xv.w;
  __shared__ float ws1[4], ws2[4];
  float sw = wave_sum64(s), s2w = wave_sum64(s2);
  int lane = t & 63, wid = t >> 6;
  if (lane == 0) { ws1[wid] = sw; ws2[wid] = s2w; }
  __syncthreads();
  float mu  = (ws1[0] + ws1[1] + ws1[2] + ws1[3]) * (1.0f / CDIM);
  float var = (ws2[0] + ws2[1] + ws2[2] + ws2[3]) * (1.0f / CDIM) - mu * mu;
  float rstd = rsqrtf(var + EPSV);
  const float* mods = mod + (size_t)b * MODC;
  float4 gv = ((const float4*)g)[t];
  float4 bv = ((const float4*)bta)[t];
  float4 sc = ((const float4*)(mods + scale_off))[t];
  float4 sh = ((const float4*)(mods + shift_off))[t];
  ushort4 ov;
  ov.x = f2bf(((xv.x - mu) * rstd * gv.x + bv.x) * (1.0f + sc.x) + sh.x);
  ov.y = f2bf(((xv.y - mu) * rstd * gv.y + bv.y) * (1.0f + sc.y) + sh.y);
  ov.z = f2bf(((xv.z - mu) * rstd * gv.z + bv.z) * (1.0f + sc.z) + sh.z);
  ov.w = f2bf(((xv.w - mu) * rstd * gv.w + bv.w) * (1.0f + sc.w) + sh.w);
  ((ushort4*)(out + (size_t)r * CDIM))[t] = ov;
}

// ---------------------------------------------------------------------------
// K3: ALL weight transpose-casts in one launch.  W[K][N] f32 -> Wt[N][K] bf16
// bid: [0,4096) four 1024^2 mats; [4096,8192) W1; [8192,12288) W2.
// ---------------------------------------------------------------------------
__global__ __launch_bounds__(256) void wcast_all(
    const float* __restrict__ Wq, const float* __restrict__ Wk,
    const float* __restrict__ Wv, const float* __restrict__ Wo,
    const float* __restrict__ W1, const float* __restrict__ W2,
    unsigned short* __restrict__ Wqkvt, unsigned short* __restrict__ Wot,
    unsigned short* __restrict__ W1t, unsigned short* __restrict__ W2t) {
  int bid = blockIdx.x;
  const float* W; unsigned short* Wt; int K, N, t;
  if (bid < 4096) {
    int m = bid >> 10;
    t = bid & 1023;
    K = CDIM; N = CDIM;
    W  = (m == 0) ? Wq : (m == 1) ? Wk : (m == 2) ? Wv : Wo;
    Wt = (m == 3) ? Wot : (Wqkvt + (size_t)m * CDIM * CDIM);
  } else if (bid < 8192) {
    t = bid - 4096; K = CDIM; N = MLPD; W = W1; Wt = W1t;
  } else {
    t = bid - 8192; K = MLPD; N = CDIM; W = W2; Wt = W2t;
  }
  int ntiles = N >> 5;
  int n0 = (t % ntiles) * 32, k0 = (t / ntiles) * 32;
  __shared__ float tile[32][33];
  int tx = threadIdx.x & 31, ty = threadIdx.x >> 5;
  #pragma unroll
  for (int p = 0; p < 4; ++p)
    tile[ty + p * 8][tx] = W[(size_t)(k0 + ty + p * 8) * N + n0 + tx];
  __syncthreads();
  #pragma unroll
  for (int p = 0; p < 4; ++p)
    Wt[(size_t)(n0 + ty + p * 8) * K + k0 + tx] = f2bf(tile[tx][ty + p * 8]);
}

// ---------------------------------------------------------------------------
// K4: bf16 MFMA GEMM, 128x128 tile (m97 structure).
// mode 0: QKV -> bf16 rows into Ob/Ob2/Ob3   mode 1: exact GELU -> Ob
// ---------------------------------------------------------------------------
__global__ __launch_bounds__(256) void mfma_gemm(
    const unsigned short* __restrict__ A,   // [M][K] bf16
    const unsigned short* __restrict__ Bt,  // [N][K] bf16
    int M, int N, int K,
    unsigned short* __restrict__ Ob, unsigned short* __restrict__ Ob2,
    unsigned short* __restrict__ Ob3, int mode) {
  __shared__ unsigned short As[128 * 32];
  __shared__ unsigned short Bs[128 * 32];
  int tid = threadIdx.x;
  int wave = tid >> 6, lane = tid & 63;
  int quad = lane >> 4, l15 = lane & 15;
  int m0 = blockIdx.y * 128, n0 = blockIdx.x * 128;
  int wm = (wave >> 1) * 64, wn = (wave & 1) * 64;

  f4v acc[4][4] = {};
  int srow = lane >> 2;
  int scol = (lane & 3) * 8;

  for (int k0 = 0; k0 < K; k0 += 32) {
    __syncthreads();
    #pragma unroll
    for (int s = 0; s < 2; ++s) {
      int inst = 2 * wave + s;
      const unsigned short* ga =
          A + (size_t)(m0 + inst * 16 + srow) * K + k0 + scol;
      __builtin_amdgcn_global_load_lds(
          (const __attribute__((address_space(1))) unsigned int*)(const void*)ga,
          (__attribute__((address_space(3))) unsigned int*)(void*)(As + inst * 512),
          16, 0, 0);
      const unsigned short* gb =
          Bt + (size_t)(n0 + inst * 16 + srow) * K + k0 + scol;
      __builtin_amdgcn_global_load_lds(
          (const __attribute__((address_space(1))) unsigned int*)(const void*)gb,
          (__attribute__((address_space(3))) unsigned int*)(void*)(Bs + inst * 512),
          16, 0, 0);
    }
    __syncthreads();

    s8v af[4], bf[4];
    #pragma unroll
    for (int i = 0; i < 4; ++i)
      af[i] = *(const s8v*)(As + ((wm + i * 16 + l15) * 32 + quad * 8));
    #pragma unroll
    for (int j = 0; j < 4; ++j)
      bf[j] = *(const s8v*)(Bs + ((wn + j * 16 + l15) * 32 + quad * 8));
    #pragma unroll
    for (int i = 0; i < 4; ++i)
      #pragma unroll
      for (int j = 0; j < 4; ++j)
        acc[i][j] = __builtin_amdgcn_mfma_f32_16x16x32_bf16(
            af[i], bf[j], acc[i][j], 0, 0, 0);
  }

  #pragma unroll
  for (int i = 0; i < 4; ++i) {
    int rbase = m0 + wm + i * 16 + quad * 4;
    #pragma unroll
    for (int j = 0; j < 4; ++j) {
      int c = n0 + wn + j * 16 + l15;
      #pragma unroll
      for (int rg = 0; rg < 4; ++rg) {
        int r = rbase + rg;
        float v = acc[i][j][rg];
        if (mode == 0) {
          unsigned short* dst = (c < 1024) ? Ob : ((c < 2048) ? Ob2 : Ob3);
          dst[(size_t)r * 1024 + (c & 1023)] = f2bf(v);
        } else {
          v = 0.5f * v * (1.0f + erff(v * 0.70710678118f));
          Ob[(size_t)r * N + c] = f2bf(v);
        }
      }
    }
  }
}

// ---------------------------------------------------------------------------
// K4b: bf16 MFMA GEMM, 64x128 tile.  O0 = res + mod[gate] * acc (fp32 out)
// ---------------------------------------------------------------------------
__global__ __launch_bounds__(256) void mfma_gemm64(
    const unsigned short* __restrict__ A,
    const unsigned short* __restrict__ Bt,
    int M, int N, int K,
    float* __restrict__ O0,
    const float* __restrict__ res, const float* __restrict__ mod,
    int gate_off) {
  __shared__ unsigned short As[64 * 32];
  __shared__ unsigned short Bs[128 * 32];
  int tid = threadIdx.x;
  int wave = tid >> 6, lane = tid & 63;
  int quad = lane >> 4, l15 = lane & 15;
  int m0 = blockIdx.y * 64, n0 = blockIdx.x * 128;
  int wm = (wave >> 1) * 32, wn = (wave & 1) * 64;

  f4v acc[2][4] = {};
  int srow = lane >> 2;
  int scol = (lane & 3) * 8;

  for (int k0 = 0; k0 < K; k0 += 32) {
    __syncthreads();
    {
      const unsigned short* ga =
          A + (size_t)(m0 + wave * 16 + srow) * K + k0 + scol;
      __builtin_amdgcn_global_load_lds(
          (const __attribute__((address_space(1))) unsigned int*)(const void*)ga,
          (__attribute__((address_space(3))) unsigned int*)(void*)(As + wave * 512),
          16, 0, 0);
    }
    #pragma unroll
    for (int s = 0; s < 2; ++s) {
      int inst = 2 * wave + s;
      const unsigned short* gb =
          Bt + (size_t)(n0 + inst * 16 + srow) * K + k0 + scol;
      __builtin_amdgcn_global_load_lds(
          (const __attribute__((address_space(1))) unsigned int*)(const void*)gb,
          (__attribute__((address_space(3))) unsigned int*)(void*)(Bs + inst * 512),
          16, 0, 0);
    }
    __syncthreads();

    s8v af[2], bf[4];
    #pragma unroll
    for (int i = 0; i < 2; ++i)
      af[i] = *(const s8v*)(As + ((wm + i * 16 + l15) * 32 + quad * 8));
    #pragma unroll
    for (int j = 0; j < 4; ++j)
      bf[j] = *(const s8v*)(Bs + ((wn + j * 16 + l15) * 32 + quad * 8));
    #pragma unroll
    for (int i = 0; i < 2; ++i)
      #pragma unroll
      for (int j = 0; j < 4; ++j)
        acc[i][j] = __builtin_amdgcn_mfma_f32_16x16x32_bf16(
            af[i], bf[j], acc[i][j], 0, 0, 0);
  }

  #pragma unroll
  for (int i = 0; i < 2; ++i) {
    int rbase = m0 + wm + i * 16 + quad * 4;
    #pragma unroll
    for (int j = 0; j < 4; ++j) {
      int c = n0 + wn + j * 16 + l15;
      #pragma unroll
      for (int rg = 0; rg < 4; ++rg) {
        int r = rbase + rg;
        int bb2 = r >> 11;
        float v = res[(size_t)r * N + c] + mod[bb2 * MODC + gate_off + c] * acc[i][j][rg];
        O0[(size_t)r * N + c] = v;
      }
    }
  }
}

// ---------------------------------------------------------------------------
// K5: fused RoPE for q and k (blockIdx.y selects buffer), bf16 in-place.
// ---------------------------------------------------------------------------
__global__ __launch_bounds__(256) void rope2_bf16(
    unsigned short* __restrict__ qb, unsigned short* __restrict__ kb,
    float qscale) {
  int r = blockIdx.x;            // b*N + n
  int n = r % NN;
  int t = threadIdx.x;
  unsigned short* buf = blockIdx.y ? kb : qb;
  float scale = blockIdx.y ? 1.0f : qscale;
  __shared__ float row[CDIM];
  __shared__ float csv[32], snv[32];
  if (t < 32) {
    float invf = powf(10000.0f, -(float)t / 32.0f);
    float sn, cs;
    sincosf((float)n * invf, &sn, &cs);
    csv[t] = cs * scale; snv[t] = sn * scale;
  }
  unsigned short* qr = buf + (size_t)r * CDIM;
  ushort4 xv = ((const ushort4*)qr)[t];
  row[t * 4 + 0] = bf2f(xv.x);
  row[t * 4 + 1] = bf2f(xv.y);
  row[t * 4 + 2] = bf2f(xv.z);
  row[t * 4 + 3] = bf2f(xv.w);
  __syncthreads();
  unsigned short o[4];
  #pragma unroll
  for (int q4 = 0; q4 < 4; ++q4) {
    int c = t * 4 + q4;
    int h = c >> 6, d = c & 63;
    int i = d & 31;
    float rh = (d < 32) ? -row[h * 64 + 2 * d + 1] : row[h * 64 + 2 * (d - 32)];
    o[q4] = f2bf(row[c] * csv[i] + rh * snv[i]);
  }
  ((ushort4*)qr)[t] = make_ushort4(o[0], o[1], o[2], o[3]);
}

// ---------------------------------------------------------------------------
// K5b: V transpose with per-64-group key PERMUTATION:
// output position p holds original key (p&3)*16 + (p>>2).  This matches the
// P-fragment storage order in fattn (PV dot-product is key-order invariant).
// ---------------------------------------------------------------------------
__global__ __launch_bounds__(256) void vtrans(
    const unsigned int* __restrict__ v,     // [B*N][512] u32 (bf16 pairs)
    unsigned short* __restrict__ vtb) {     // [B*H][64][2048] bf16, permuted
  int nb = blockIdx.x;
  int bh = blockIdx.y;
  int b = bh >> 4, h = bh & 15;
  __shared__ unsigned int Ts[64][33];
  int n0 = nb * 64;
  int tid = threadIdx.x;
  int col = tid & 31, r0 = tid >> 5;
  #pragma unroll
  for (int p = 0; p < 8; ++p) {
    int row = r0 + p * 8;
    Ts[row][col] = v[(size_t)(b * NN + n0 + row) * 512 + h * 32 + col];
  }
  __syncthreads();
  int np = tid & 31, d0 = tid >> 5;
  #pragma unroll
  for (int i = 0; i < 8; ++i) {
    int d = d0 * 8 + i;
    int p0 = 2 * np;                        // even output position
    int kt = p0 & 3, lp = p0 >> 2;
    int key0 = kt * 16 + lp;                // original keys for p0, p0+1
    int key1 = (kt + 1) * 16 + lp;
    unsigned int w0 = Ts[key0][d >> 1];
    unsigned int w1 = Ts[key1][d >> 1];
    unsigned int a  = (d & 1) ? (w0 >> 16) : (w0 & 0xffffu);
    unsigned int c2 = (d & 1) ? (w1 >> 16) : (w1 & 0xffffu);
    ((unsigned int*)(vtb + ((size_t)bh * 64 + d) * NN + n0))[np] =
        a | (c2 << 16);
  }
}

// ---------------------------------------------------------------------------
// K6: barrier-free MFMA flash attention. K/V fragments loaded DIRECTLY from
// global (L2-resident; bid swizzle keeps each bh's K/V on one XCD residue).
// Only P round-trips through wave-private LDS (permuted keys -> b64 writes).
// Q pre-scaled by (1/8)*log2(e); softmax in exp2 units.
// ---------------------------------------------------------------------------
__global__ __launch_bounds__(256, 4) void fattn_direct(
    const unsigned short* __restrict__ qb,   // [B*N][1024] (scaled)
    const unsigned short* __restrict__ kb,   // [B*N][1024]
    const unsigned short* __restrict__ vtb,  // [B*H][64][2048] (key-permuted)
    unsigned short* __restrict__ ob) {       // [B*N][1024]
  int bid = blockIdx.x;
  int qt = bid >> 5, bh = bid & 31;          // bid%8 == bh%8 -> XCD locality
  int b = bh >> 4, h = bh & 15;
  int tid = threadIdx.x;
  int wave = tid >> 6, lane = tid & 63;
  int quad = lane >> 4, l15 = lane & 15;

  __shared__ unsigned short Ps[4][16 * 72];  // per-wave P[q][key'], stride 72

  int n0 = qt * 64;
  int qrow = n0 + wave * 16 + l15;
  s8v qf[2];
  {
    const unsigned short* qp = qb + (size_t)(b * NN + qrow) * CDIM + h * HDIM;
    qf[0] = *(const s8v*)(qp + quad * 8);
    qf[1] = *(const s8v*)(qp + 32 + quad * 8);
  }

  f4v acc[4] = {};
  float m_i[4], l_i[4];
  #pragma unroll
  for (int r = 0; r < 4; ++r) { m_i[r] = -1e30f; l_i[r] = 0.f; }

  // per-lane bases: K rows by key, V^T rows by d
  const unsigned short* kgl =
      kb + (size_t)(b * NN + l15) * CDIM + h * HDIM + quad * 8;
  const unsigned short* vgl =
      vtb + ((size_t)bh * 64 + l15) * NN + quad * 8;
  unsigned short* Pw = Ps[wave];

  for (int t = 0; t < NN / 64; ++t) {
    int kk0 = t * 64;
    // ---- K fragments direct from global (B[n=key][k=d]) ----
    s8v kf[4][2];
    #pragma unroll
    for (int kt = 0; kt < 4; ++kt) {
      const unsigned short* kp = kgl + (size_t)(kk0 + kt * 16) * CDIM;
      kf[kt][0] = *(const s8v*)(kp);
      kf[kt][1] = *(const s8v*)(kp + 32);
    }
    // ---- V fragments direct from global (B[n=d][k=key']), issued early ----
    s8v vf[4][2];
    #pragma unroll
    for (int dt = 0; dt < 4; ++dt) {
      const unsigned short* vp = vgl + (size_t)(dt * 16) * NN + kk0;
      vf[dt][0] = *(const s8v*)(vp);
      vf[dt][1] = *(const s8v*)(vp + 32);
    }

    // ---- S = Q K^T ----
    f4v s4[4] = {};
    #pragma unroll
    for (int kt = 0; kt < 4; ++kt) {
      s4[kt] = __builtin_amdgcn_mfma_f32_16x16x32_bf16(qf[0], kf[kt][0], s4[kt], 0, 0, 0);
      s4[kt] = __builtin_amdgcn_mfma_f32_16x16x32_bf16(qf[1], kf[kt][1], s4[kt], 0, 0, 0);
    }

    // ---- online softmax (exp2 units; l-sum stays per-lane partial) ----
    #pragma unroll
    for (int r = 0; r < 4; ++r) {
      float mv = fmaxf(fmaxf(s4[0][r], s4[1][r]), fmaxf(s4[2][r], s4[3][r]));
      #pragma unroll
      for (int msk = 1; msk < 16; msk <<= 1)
        mv = fmaxf(mv, __shfl_xor(mv, msk, 64));
      float mnew = fmaxf(m_i[r], mv);
      float alpha = __builtin_amdgcn_exp2f(m_i[r] - mnew);
      m_i[r] = mnew;
      float ls = 0.f;
      #pragma unroll
      for (int kt = 0; kt < 4; ++kt) {
        float p = __builtin_amdgcn_exp2f(s4[kt][r] - mnew);
        s4[kt][r] = p;
        ls += p;
      }
      l_i[r] = l_i[r] * alpha + ls;
      acc[0][r] *= alpha; acc[1][r] *= alpha;
      acc[2][r] *= alpha; acc[3][r] *= alpha;
    }

    // ---- P -> wave-private LDS, permuted keys: key' = l15*4 + kt ----
    // row q = quad*4+r; 4 kt values pack into one b64 write (conflict-free).
    #pragma unroll
    for (int r = 0; r < 4; ++r) {
      unsigned int lo = (__float_as_uint(s4[0][r]) >> 16) |
                        (__float_as_uint(s4[1][r]) & 0xffff0000u);
      unsigned int hi = (__float_as_uint(s4[2][r]) >> 16) |
                        (__float_as_uint(s4[3][r]) & 0xffff0000u);
      *(uint2*)(Pw + (quad * 4 + r) * 72 + l15 * 4) = make_uint2(lo, hi);
    }

    s8v pf0 = *(const s8v*)(Pw + l15 * 72 + quad * 8);        // keys' 0..31
    s8v pf1 = *(const s8v*)(Pw + l15 * 72 + 32 + quad * 8);   // keys' 32..63

    // ---- acc += P V  (V side uses the same permuted key order) ----
    #pragma unroll
    for (int dt = 0; dt < 4; ++dt) {
      acc[dt] = __builtin_amdgcn_mfma_f32_16x16x32_bf16(pf0, vf[dt][0], acc[dt], 0, 0, 0);
      acc[dt] = __builtin_amdgcn_mfma_f32_16x16x32_bf16(pf1, vf[dt][1], acc[dt], 0, 0, 0);
    }
  }

  // ---- epilogue: finish l reduction, normalize, store ----
  #pragma unroll
  for (int r = 0; r < 4; ++r) {
    float l = l_i[r];
    #pragma unroll
    for (int msk = 1; msk < 16; msk <<= 1)
      l += __shfl_xor(l, msk, 64);
    float inv = 1.0f / l;
    size_t row = (size_t)(b * NN + n0 + wave * 16 + quad * 4 + r);
    unsigned short* op = ob + row * CDIM + h * HDIM;
    #pragma unroll
    for (int dt = 0; dt < 4; ++dt)
      op[dt * 16 + l15] = f2bf(acc[dt][r] * inv);
  }
}

// ---------------------------------------------------------------------------
extern "C" void kernel_launch(void* const* d_in, const int* in_sizes, int n_in,
                              void* d_out, int out_size, void* d_ws, size_t ws_size,
                              hipStream_t stream) {
  const float* x    = (const float*)d_in[0];
  const float* temb = (const float*)d_in[1];
  const float* n1g  = (const float*)d_in[2];
  const float* n1b  = (const float*)d_in[3];
  const float* Wq   = (const float*)d_in[4];
  const float* Wk   = (const float*)d_in[5];
  const float* Wv   = (const float*)d_in[6];
  const float* Wo   = (const float*)d_in[7];
  const float* n2g  = (const float*)d_in[8];
  const float* n2b  = (const float*)d_in[9];
  const float* W1   = (const float*)d_in[10];
  const float* W2   = (const float*)d_in[11];
  const float* adaW = (const float*)d_in[12];
  const float* adab = (const float*)d_in[13];
  float* out = (float*)d_out;

  const size_t TOK = (size_t)BB * NN * CDIM;   // 4,194,304
  float* wsf = (float*)d_ws;
  float* mod = wsf;                                        // 16384 f32
  unsigned short* tokb  = (unsigned short*)(wsf + 16384);  // TOK u16
  unsigned short* qb    = tokb + TOK;
  unsigned short* kb    = qb + TOK;
  unsigned short* vtb   = kb + TOK;
  unsigned short* Wqkvt = vtb + TOK;                       // 3M u16
  unsigned short* Wot   = Wqkvt + 3 * CDIM * CDIM;         // 1M
  unsigned short* W1t   = Wot + CDIM * CDIM;               // 4M
  unsigned short* W2t   = W1t + CDIM * MLPD;               // 4M
  unsigned short* h1b   = W2t + MLPD * CDIM;               // 16.7M u16
  unsigned short* vrow  = h1b;          // staging alias (dead before W1 GEMM)
  float* x1 = (float*)qb;               // fp32 alias over qb+kb

  const int M = BB * NN;   // 4096

  mod_kernel<<<dim3(MODC / 256, BB), 256, 0, stream>>>(temb, adaW, adab, mod);
  ln_mod_bf16<<<dim3(M), 256, 0, stream>>>(x, n1g, n1b, mod, 0, 1024, tokb);

  wcast_all<<<dim3(12288), 256, 0, stream>>>(
      Wq, Wk, Wv, Wo, W1, W2, Wqkvt, Wot, W1t, W2t);

  // fused QKV -> q,k,v row-major bf16
  mfma_gemm<<<dim3(24, 32), 256, 0, stream>>>(
      tokb, Wqkvt, M, 3 * CDIM, CDIM, qb, kb, vrow, 0);

  rope2_bf16<<<dim3(M, 2), 256, 0, stream>>>(qb, kb, 0.125f * LOG2E);

  vtrans<<<dim3(NN / 64, BB * HEADS), 256, 0, stream>>>(
      (const unsigned int*)vrow, vtb);

  fattn_direct<<<dim3((NN / 64) * BB * HEADS), 256, 0, stream>>>(
      qb, kb, vtb, tokb);

  // x1 = x + gate_msa * (attn @ Wo)
  mfma_gemm64<<<dim3(CDIM / 128, M / 64), 256, 0, stream>>>(
      tokb, Wot, M, CDIM, CDIM, x1, x, mod, 2048);

  ln_mod_bf16<<<dim3(M), 256, 0, stream>>>(x1, n2g, n2b, mod, 3072, 4096, tokb);

  // h1 = gelu(xn2 @ W1)
  mfma_gemm<<<dim3(MLPD / 128, M / 128), 256, 0, stream>>>(
      tokb, W1t, M, MLPD, CDIM, h1b, nullptr, nullptr, 1);

  // out = x1 + gate_mlp * (h1 @ W2)
  mfma_gemm64<<<dim3(CDIM / 128, M / 64), 256, 0, stream>>>(
      h1b, W2t, M, CDIM, MLPD, out, x1, mod, 5120);
}

// Round 7
// 467.002 us; speedup vs baseline: 1.3860x; 1.3860x over previous
//
#include <hip/hip_runtime.h>
#include <math.h>

#define BB    2
#define NN    2048
#define CDIM  1024
#define HEADS 16
#define HDIM  64
#define MLPD  4096
#define MODC  6144
#define EPSV  1e-5f
#define LOG2E 1.4426950408889634f
#define MSPLIT 16

typedef __attribute__((ext_vector_type(8))) short s8v;     // 8 bf16 (4 VGPRs)
typedef __attribute__((ext_vector_type(4))) float f4v;     // MFMA C/D

__device__ inline unsigned short f2bf(float f) {
  union { float f; unsigned u; } v; v.f = f;
  unsigned r = v.u + 0x7FFFu + ((v.u >> 16) & 1u);   // RNE
  return (unsigned short)(r >> 16);
}
__device__ inline float bf2f(unsigned short h) {
  union { unsigned u; float f; } v; v.u = ((unsigned)h) << 16;
  return v.f;
}

// ---------------------------------------------------------------------------
// K1a: split-K partials for mod = silu(t_emb) @ ada_W
// grid (MODC/256, B, MSPLIT); each block: 256 cols x 64 k-rows
// ---------------------------------------------------------------------------
__global__ __launch_bounds__(256) void mod_part(
    const float* __restrict__ t_emb, const float* __restrict__ ada_W,
    float* __restrict__ part) {
  int j = blockIdx.x * 256 + threadIdx.x;
  int b = blockIdx.y, ks = blockIdx.z;
  __shared__ float st[64];
  if (threadIdx.x < 64) {
    float v = t_emb[b * CDIM + ks * 64 + threadIdx.x];
    st[threadIdx.x] = v / (1.0f + expf(-v));
  }
  __syncthreads();
  float acc = 0.f;
  const float* wp = ada_W + (size_t)(ks * 64) * MODC + j;
  #pragma unroll 8
  for (int i = 0; i < 64; ++i) acc += st[i] * wp[(size_t)i * MODC];
  part[((size_t)ks * BB + b) * MODC + j] = acc;
}

// K1b: reduce partials + bias
__global__ __launch_bounds__(256) void mod_reduce(
    const float* __restrict__ part, const float* __restrict__ ada_b,
    float* __restrict__ mod) {
  int idx = blockIdx.x * 256 + threadIdx.x;   // 0 .. B*MODC-1
  int b = idx / MODC, j = idx % MODC;
  float a = ada_b[j];
  #pragma unroll
  for (int s = 0; s < MSPLIT; ++s) a += part[((size_t)s * BB + b) * MODC + j];
  mod[(size_t)b * MODC + j] = a;
}

// ---------------------------------------------------------------------------
// K2: LN + adaLN modulation, bf16 output
// ---------------------------------------------------------------------------
__device__ inline float wave_sum64(float v) {
  for (int o = 32; o > 0; o >>= 1) v += __shfl_down(v, o, 64);
  return v;
}

__global__ __launch_bounds__(256) void ln_mod_bf16(
    const float* __restrict__ x, const float* __restrict__ g,
    const float* __restrict__ bta, const float* __restrict__ mod,
    int shift_off, int scale_off, unsigned short* __restrict__ out) {
  int r = blockIdx.x;
  int b = r / NN;
  int t = threadIdx.x;
  const float* xr = x + (size_t)r * CDIM;
  float4 xv = ((const float4*)xr)[t];
  float s  = xv.x + xv.y + xv.z + xv.w;
  float s2 = xv.x*xv.x + xv.y*xv.y + xv.z*xv.z + xv.w*xv.w;
  __shared__ float ws1[4], ws2[4];
  float sw = wave_sum64(s), s2w = wave_sum64(s2);
  int lane = t & 63, wid = t >> 6;
  if (lane == 0) { ws1[wid] = sw; ws2[wid] = s2w; }
  __syncthreads();
  float mu  = (ws1[0] + ws1[1] + ws1[2] + ws1[3]) * (1.0f / CDIM);
  float var = (ws2[0] + ws2[1] + ws2[2] + ws2[3]) * (1.0f / CDIM) - mu * mu;
  float rstd = rsqrtf(var + EPSV);
  const float* mods = mod + (size_t)b * MODC;
  float4 gv = ((const float4*)g)[t];
  float4 bv = ((const float4*)bta)[t];
  float4 sc = ((const float4*)(mods + scale_off))[t];
  float4 sh = ((const float4*)(mods + shift_off))[t];
  ushort4 ov;
  ov.x = f2bf(((xv.x - mu) * rstd * gv.x + bv.x) * (1.0f + sc.x) + sh.x);
  ov.y = f2bf(((xv.y - mu) * rstd * gv.y + bv.y) * (1.0f + sc.y) + sh.y);
  ov.z = f2bf(((xv.z - mu) * rstd * gv.z + bv.z) * (1.0f + sc.z) + sh.z);
  ov.w = f2bf(((xv.w - mu) * rstd * gv.w + bv.w) * (1.0f + sc.w) + sh.w);
  ((ushort4*)(out + (size_t)r * CDIM))[t] = ov;
}

// ---------------------------------------------------------------------------
// K3: ALL weight transpose-casts in one launch.  W[K][N] f32 -> Wt[N][K] bf16
// ---------------------------------------------------------------------------
__global__ __launch_bounds__(256) void wcast_all(
    const float* __restrict__ Wq, const float* __restrict__ Wk,
    const float* __restrict__ Wv, const float* __restrict__ Wo,
    const float* __restrict__ W1, const float* __restrict__ W2,
    unsigned short* __restrict__ Wqkvt, unsigned short* __restrict__ Wot,
    unsigned short* __restrict__ W1t, unsigned short* __restrict__ W2t) {
  int bid = blockIdx.x;
  const float* W; unsigned short* Wt; int K, N, t;
  if (bid < 4096) {
    int m = bid >> 10;
    t = bid & 1023;
    K = CDIM; N = CDIM;
    W  = (m == 0) ? Wq : (m == 1) ? Wk : (m == 2) ? Wv : Wo;
    Wt = (m == 3) ? Wot : (Wqkvt + (size_t)m * CDIM * CDIM);
  } else if (bid < 8192) {
    t = bid - 4096; K = CDIM; N = MLPD; W = W1; Wt = W1t;
  } else {
    t = bid - 8192; K = MLPD; N = CDIM; W = W2; Wt = W2t;
  }
  int ntiles = N >> 5;
  int n0 = (t % ntiles) * 32, k0 = (t / ntiles) * 32;
  __shared__ float tile[32][33];
  int tx = threadIdx.x & 31, ty = threadIdx.x >> 5;
  #pragma unroll
  for (int p = 0; p < 4; ++p)
    tile[ty + p * 8][tx] = W[(size_t)(k0 + ty + p * 8) * N + n0 + tx];
  __syncthreads();
  #pragma unroll
  for (int p = 0; p < 4; ++p)
    Wt[(size_t)(n0 + ty + p * 8) * K + k0 + tx] = f2bf(tile[tx][ty + p * 8]);
}

// ---------------------------------------------------------------------------
// K4: bf16 MFMA GEMM, 128x128 tile (m97 structure).
// mode 0: QKV -> bf16 rows into Ob/Ob2/Ob3   mode 1: exact GELU -> Ob
// ---------------------------------------------------------------------------
__global__ __launch_bounds__(256) void mfma_gemm(
    const unsigned short* __restrict__ A,
    const unsigned short* __restrict__ Bt,
    int M, int N, int K,
    unsigned short* __restrict__ Ob, unsigned short* __restrict__ Ob2,
    unsigned short* __restrict__ Ob3, int mode) {
  __shared__ unsigned short As[128 * 32];
  __shared__ unsigned short Bs[128 * 32];
  int tid = threadIdx.x;
  int wave = tid >> 6, lane = tid & 63;
  int quad = lane >> 4, l15 = lane & 15;
  int m0 = blockIdx.y * 128, n0 = blockIdx.x * 128;
  int wm = (wave >> 1) * 64, wn = (wave & 1) * 64;

  f4v acc[4][4] = {};
  int srow = lane >> 2;
  int scol = (lane & 3) * 8;

  for (int k0 = 0; k0 < K; k0 += 32) {
    __syncthreads();
    #pragma unroll
    for (int s = 0; s < 2; ++s) {
      int inst = 2 * wave + s;
      const unsigned short* ga =
          A + (size_t)(m0 + inst * 16 + srow) * K + k0 + scol;
      __builtin_amdgcn_global_load_lds(
          (const __attribute__((address_space(1))) unsigned int*)(const void*)ga,
          (__attribute__((address_space(3))) unsigned int*)(void*)(As + inst * 512),
          16, 0, 0);
      const unsigned short* gb =
          Bt + (size_t)(n0 + inst * 16 + srow) * K + k0 + scol;
      __builtin_amdgcn_global_load_lds(
          (const __attribute__((address_space(1))) unsigned int*)(const void*)gb,
          (__attribute__((address_space(3))) unsigned int*)(void*)(Bs + inst * 512),
          16, 0, 0);
    }
    __syncthreads();

    s8v af[4], bf[4];
    #pragma unroll
    for (int i = 0; i < 4; ++i)
      af[i] = *(const s8v*)(As + ((wm + i * 16 + l15) * 32 + quad * 8));
    #pragma unroll
    for (int j = 0; j < 4; ++j)
      bf[j] = *(const s8v*)(Bs + ((wn + j * 16 + l15) * 32 + quad * 8));
    #pragma unroll
    for (int i = 0; i < 4; ++i)
      #pragma unroll
      for (int j = 0; j < 4; ++j)
        acc[i][j] = __builtin_amdgcn_mfma_f32_16x16x32_bf16(
            af[i], bf[j], acc[i][j], 0, 0, 0);
  }

  #pragma unroll
  for (int i = 0; i < 4; ++i) {
    int rbase = m0 + wm + i * 16 + quad * 4;
    #pragma unroll
    for (int j = 0; j < 4; ++j) {
      int c = n0 + wn + j * 16 + l15;
      #pragma unroll
      for (int rg = 0; rg < 4; ++rg) {
        int r = rbase + rg;
        float v = acc[i][j][rg];
        if (mode == 0) {
          unsigned short* dst = (c < 1024) ? Ob : ((c < 2048) ? Ob2 : Ob3);
          dst[(size_t)r * 1024 + (c & 1023)] = f2bf(v);
        } else {
          v = 0.5f * v * (1.0f + erff(v * 0.70710678118f));
          Ob[(size_t)r * N + c] = f2bf(v);
        }
      }
    }
  }
}

// ---------------------------------------------------------------------------
// K4b: bf16 MFMA GEMM, 64x128 tile.  O0 = res + mod[gate] * acc (fp32 out)
// ---------------------------------------------------------------------------
__global__ __launch_bounds__(256) void mfma_gemm64(
    const unsigned short* __restrict__ A,
    const unsigned short* __restrict__ Bt,
    int M, int N, int K,
    float* __restrict__ O0,
    const float* __restrict__ res, const float* __restrict__ mod,
    int gate_off) {
  __shared__ unsigned short As[64 * 32];
  __shared__ unsigned short Bs[128 * 32];
  int tid = threadIdx.x;
  int wave = tid >> 6, lane = tid & 63;
  int quad = lane >> 4, l15 = lane & 15;
  int m0 = blockIdx.y * 64, n0 = blockIdx.x * 128;
  int wm = (wave >> 1) * 32, wn = (wave & 1) * 64;

  f4v acc[2][4] = {};
  int srow = lane >> 2;
  int scol = (lane & 3) * 8;

  for (int k0 = 0; k0 < K; k0 += 32) {
    __syncthreads();
    {
      const unsigned short* ga =
          A + (size_t)(m0 + wave * 16 + srow) * K + k0 + scol;
      __builtin_amdgcn_global_load_lds(
          (const __attribute__((address_space(1))) unsigned int*)(const void*)ga,
          (__attribute__((address_space(3))) unsigned int*)(void*)(As + wave * 512),
          16, 0, 0);
    }
    #pragma unroll
    for (int s = 0; s < 2; ++s) {
      int inst = 2 * wave + s;
      const unsigned short* gb =
          Bt + (size_t)(n0 + inst * 16 + srow) * K + k0 + scol;
      __builtin_amdgcn_global_load_lds(
          (const __attribute__((address_space(1))) unsigned int*)(const void*)gb,
          (__attribute__((address_space(3))) unsigned int*)(void*)(Bs + inst * 512),
          16, 0, 0);
    }
    __syncthreads();

    s8v af[2], bf[4];
    #pragma unroll
    for (int i = 0; i < 2; ++i)
      af[i] = *(const s8v*)(As + ((wm + i * 16 + l15) * 32 + quad * 8));
    #pragma unroll
    for (int j = 0; j < 4; ++j)
      bf[j] = *(const s8v*)(Bs + ((wn + j * 16 + l15) * 32 + quad * 8));
    #pragma unroll
    for (int i = 0; i < 2; ++i)
      #pragma unroll
      for (int j = 0; j < 4; ++j)
        acc[i][j] = __builtin_amdgcn_mfma_f32_16x16x32_bf16(
            af[i], bf[j], acc[i][j], 0, 0, 0);
  }

  #pragma unroll
  for (int i = 0; i < 2; ++i) {
    int rbase = m0 + wm + i * 16 + quad * 4;
    #pragma unroll
    for (int j = 0; j < 4; ++j) {
      int c = n0 + wn + j * 16 + l15;
      #pragma unroll
      for (int rg = 0; rg < 4; ++rg) {
        int r = rbase + rg;
        int bb2 = r >> 11;
        float v = res[(size_t)r * N + c] + mod[bb2 * MODC + gate_off + c] * acc[i][j][rg];
        O0[(size_t)r * N + c] = v;
      }
    }
  }
}

// ---------------------------------------------------------------------------
// K5: fused RoPE. y=0: q in-place (scaled by 1/8*log2e). y=1: k -> kpack
// kpack layout: [bh][t][f=kt*2+half][lane=quad*16+l15][8], u16.
// key = t*64 + kt*16 + l15, d = half*32 + quad*8 + j.
// ---------------------------------------------------------------------------
__global__ __launch_bounds__(256) void rope_qk(
    unsigned short* __restrict__ qb, const unsigned short* __restrict__ kb,
    unsigned short* __restrict__ kpack, float qscale) {
  int r = blockIdx.x;            // b*N + n
  int b = r / NN, n = r % NN;
  int t = threadIdx.x;
  int isK = blockIdx.y;
  const unsigned short* src = isK ? kb : qb;
  float scale = isK ? 1.0f : qscale;
  __shared__ float row[CDIM];
  __shared__ float csv[32], snv[32];
  if (t < 32) {
    float invf = powf(10000.0f, -(float)t / 32.0f);
    float sn, cs;
    sincosf((float)n * invf, &sn, &cs);
    csv[t] = cs * scale; snv[t] = sn * scale;
  }
  const unsigned short* qr = src + (size_t)r * CDIM;
  ushort4 xv = ((const ushort4*)qr)[t];
  row[t * 4 + 0] = bf2f(xv.x);
  row[t * 4 + 1] = bf2f(xv.y);
  row[t * 4 + 2] = bf2f(xv.z);
  row[t * 4 + 3] = bf2f(xv.w);
  __syncthreads();
  unsigned short o[4];
  int c0 = t * 4;
  #pragma unroll
  for (int q4 = 0; q4 < 4; ++q4) {
    int c = c0 + q4;
    int h = c >> 6, d = c & 63;
    int i = d & 31;
    float rh = (d < 32) ? -row[h * 64 + 2 * d + 1] : row[h * 64 + 2 * (d - 32)];
    o[q4] = f2bf(row[c] * csv[i] + rh * snv[i]);
  }
  if (!isK) {
    ((ushort4*)(qb + (size_t)r * CDIM))[t] = make_ushort4(o[0], o[1], o[2], o[3]);
  } else {
    int h = c0 >> 6, d0 = c0 & 63;
    int half = d0 >> 5, quad = (d0 >> 3) & 3, j0 = d0 & 7;  // j0 in {0,4}
    int bh = b * HEADS + h;
    int tt = n >> 6, kt = (n >> 4) & 3, l15 = n & 15;
    int lane = quad * 16 + l15;
    size_t off = ((((size_t)bh * 32 + tt) * 8 + kt * 2 + half) * 64 + lane) * 8 + j0;
    unsigned int lo = (unsigned)o[0] | ((unsigned)o[1] << 16);
    unsigned int hi = (unsigned)o[2] | ((unsigned)o[3] << 16);
    *(uint2*)(kpack + off) = make_uint2(lo, hi);
  }
}

// ---------------------------------------------------------------------------
// K5b: V pack  vrow[B*N][1024] -> vpack[bh][t][f=dt*2+half][lane][8]
// element: d = dt*16+l15, permuted pos p = half*32+quad*8+j,
// orig key = (p&3)*16 + (p>>2).
// ---------------------------------------------------------------------------
__global__ __launch_bounds__(256) void vtrans_pack(
    const unsigned short* __restrict__ vrow, unsigned short* __restrict__ vpack) {
  int t = blockIdx.x;
  int bh = blockIdx.y;
  int b = bh >> 4, h = bh & 15;
  __shared__ unsigned short L[64 * 72];     // L[key][d], pad 72
  int tid = threadIdx.x;
  #pragma unroll
  for (int p = 0; p < 2; ++p) {
    int c = tid + p * 256;
    int key = c >> 3, dc = (c & 7) * 8;
    *(s8v*)(L + key * 72 + dc) =
        *(const s8v*)(vrow + (size_t)(b * NN + t * 64 + key) * CDIM + h * HDIM + dc);
  }
  __syncthreads();
  #pragma unroll
  for (int p = 0; p < 2; ++p) {
    int o = tid + p * 256;
    int f = o >> 6, lane = o & 63;
    int dt = f >> 1, half = f & 1, quad = lane >> 4, l15 = lane & 15;
    int d = dt * 16 + l15;
    unsigned short tmp[8];
    #pragma unroll
    for (int j = 0; j < 8; ++j) {
      int key = (j & 3) * 16 + half * 8 + quad * 2 + (j >> 2);
      tmp[j] = L[key * 72 + d];
    }
    *(s8v*)(vpack + ((((size_t)bh * 32 + t) * 8 + f) * 64 + lane) * 8) = *(s8v*)tmp;
  }
}

// ---------------------------------------------------------------------------
// K6: barrier-free MFMA flash attention, fragment-packed K/V (coalesced:
// every fragment load is base + lane*16B). P via wave-private LDS.
// ---------------------------------------------------------------------------
__global__ __launch_bounds__(256, 4) void fattn_pack(
    const unsigned short* __restrict__ qb,     // [B*N][1024] (scaled)
    const unsigned short* __restrict__ kpack,  // [bh][32][8][64][8]
    const unsigned short* __restrict__ vpack,  // [bh][32][8][64][8]
    unsigned short* __restrict__ ob) {         // [B*N][1024]
  int bid = blockIdx.x;
  int qt = bid >> 5, bh = bid & 31;            // bid%8 == bh%8 -> XCD locality
  int b = bh >> 4, h = bh & 15;
  int tid = threadIdx.x;
  int wave = tid >> 6, lane = tid & 63;
  int quad = lane >> 4, l15 = lane & 15;

  __shared__ unsigned short Ps[4][16 * 72];    // per-wave P[q][key']

  int n0 = qt * 64;
  int qrow = n0 + wave * 16 + l15;
  s8v qf[2];
  {
    const unsigned short* qp = qb + (size_t)(b * NN + qrow) * CDIM + h * HDIM;
    qf[0] = *(const s8v*)(qp + quad * 8);
    qf[1] = *(const s8v*)(qp + 32 + quad * 8);
  }

  f4v acc[4] = {};
  float m_i[4], l_i[4];
  #pragma unroll
  for (int r = 0; r < 4; ++r) { m_i[r] = -1e30f; l_i[r] = 0.f; }

  const unsigned short* kbase = kpack + (size_t)bh * 32 * 4096 + lane * 8;
  const unsigned short* vbase = vpack + (size_t)bh * 32 * 4096 + lane * 8;
  unsigned short* Pw = Ps[wave];

  for (int t = 0; t < NN / 64; ++t) {
    const unsigned short* kt_ = kbase + (size_t)t * 4096;
    const unsigned short* vt_ = vbase + (size_t)t * 4096;
    // ---- coalesced fragment loads ----
    s8v kf[8], vf[8];
    #pragma unroll
    for (int f = 0; f < 8; ++f) kf[f] = *(const s8v*)(kt_ + f * 512);
    #pragma unroll
    for (int f = 0; f < 8; ++f) vf[f] = *(const s8v*)(vt_ + f * 512);

    // ---- S = Q K^T ----
    f4v s4[4] = {};
    #pragma unroll
    for (int kt = 0; kt < 4; ++kt) {
      s4[kt] = __builtin_amdgcn_mfma_f32_16x16x32_bf16(qf[0], kf[kt * 2], s4[kt], 0, 0, 0);
      s4[kt] = __builtin_amdgcn_mfma_f32_16x16x32_bf16(qf[1], kf[kt * 2 + 1], s4[kt], 0, 0, 0);
    }

    // ---- online softmax (exp2 units; l partial per lane) ----
    #pragma unroll
    for (int r = 0; r < 4; ++r) {
      float mv = fmaxf(fmaxf(s4[0][r], s4[1][r]), fmaxf(s4[2][r], s4[3][r]));
      #pragma unroll
      for (int msk = 1; msk < 16; msk <<= 1)
        mv = fmaxf(mv, __shfl_xor(mv, msk, 64));
      float mnew = fmaxf(m_i[r], mv);
      float alpha = __builtin_amdgcn_exp2f(m_i[r] - mnew);
      m_i[r] = mnew;
      float ls = 0.f;
      #pragma unroll
      for (int kt = 0; kt < 4; ++kt) {
        float p = __builtin_amdgcn_exp2f(s4[kt][r] - mnew);
        s4[kt][r] = p;
        ls += p;
      }
      l_i[r] = l_i[r] * alpha + ls;
      acc[0][r] *= alpha; acc[1][r] *= alpha;
      acc[2][r] *= alpha; acc[3][r] *= alpha;
    }

    // ---- P -> wave-private LDS, permuted keys (b64 writes) ----
    #pragma unroll
    for (int r = 0; r < 4; ++r) {
      unsigned int lo = (__float_as_uint(s4[0][r]) >> 16) |
                        (__float_as_uint(s4[1][r]) & 0xffff0000u);
      unsigned int hi = (__float_as_uint(s4[2][r]) >> 16) |
                        (__float_as_uint(s4[3][r]) & 0xffff0000u);
      *(uint2*)(Pw + (quad * 4 + r) * 72 + l15 * 4) = make_uint2(lo, hi);
    }

    s8v pf0 = *(const s8v*)(Pw + l15 * 72 + quad * 8);
    s8v pf1 = *(const s8v*)(Pw + l15 * 72 + 32 + quad * 8);

    // ---- acc += P V (same permuted key order baked into vpack) ----
    #pragma unroll
    for (int dt = 0; dt < 4; ++dt) {
      acc[dt] = __builtin_amdgcn_mfma_f32_16x16x32_bf16(pf0, vf[dt * 2], acc[dt], 0, 0, 0);
      acc[dt] = __builtin_amdgcn_mfma_f32_16x16x32_bf16(pf1, vf[dt * 2 + 1], acc[dt], 0, 0, 0);
    }
  }

  // ---- epilogue ----
  #pragma unroll
  for (int r = 0; r < 4; ++r) {
    float l = l_i[r];
    #pragma unroll
    for (int msk = 1; msk < 16; msk <<= 1)
      l += __shfl_xor(l, msk, 64);
    float inv = 1.0f / l;
    size_t row = (size_t)(b * NN + n0 + wave * 16 + quad * 4 + r);
    unsigned short* op = ob + row * CDIM + h * HDIM;
    #pragma unroll
    for (int dt = 0; dt < 4; ++dt)
      op[dt * 16 + l15] = f2bf(acc[dt][r] * inv);
  }
}

// ---------------------------------------------------------------------------
extern "C" void kernel_launch(void* const* d_in, const int* in_sizes, int n_in,
                              void* d_out, int out_size, void* d_ws, size_t ws_size,
                              hipStream_t stream) {
  const float* x    = (const float*)d_in[0];
  const float* temb = (const float*)d_in[1];
  const float* n1g  = (const float*)d_in[2];
  const float* n1b  = (const float*)d_in[3];
  const float* Wq   = (const float*)d_in[4];
  const float* Wk   = (const float*)d_in[5];
  const float* Wv   = (const float*)d_in[6];
  const float* Wo   = (const float*)d_in[7];
  const float* n2g  = (const float*)d_in[8];
  const float* n2b  = (const float*)d_in[9];
  const float* W1   = (const float*)d_in[10];
  const float* W2   = (const float*)d_in[11];
  const float* adaW = (const float*)d_in[12];
  const float* adab = (const float*)d_in[13];
  float* out = (float*)d_out;

  const size_t TOK = (size_t)BB * NN * CDIM;   // 4,194,304
  float* wsf = (float*)d_ws;
  float* mod     = wsf;                                    // 16384 f32
  float* modpart = wsf + 16384;                            // 16*2*6144 f32
  unsigned short* tokb  = (unsigned short*)(wsf + 16384 + MSPLIT * BB * MODC);
  unsigned short* qb    = tokb + TOK;
  unsigned short* kb    = qb + TOK;
  unsigned short* kpack = kb + TOK;
  unsigned short* vpack = kpack + TOK;
  unsigned short* Wqkvt = vpack + TOK;                     // 3M u16
  unsigned short* Wot   = Wqkvt + 3 * CDIM * CDIM;         // 1M
  unsigned short* W1t   = Wot + CDIM * CDIM;               // 4M
  unsigned short* W2t   = W1t + CDIM * MLPD;               // 4M
  unsigned short* h1b   = W2t + MLPD * CDIM;               // 16.7M u16
  unsigned short* vrow  = h1b;          // staging alias (dead before W1 GEMM)
  float* x1 = (float*)qb;               // fp32 alias over qb+kb (dead after fattn)

  const int M = BB * NN;   // 4096

  mod_part<<<dim3(MODC / 256, BB, MSPLIT), 256, 0, stream>>>(temb, adaW, modpart);
  mod_reduce<<<dim3(BB * MODC / 256), 256, 0, stream>>>(modpart, adab, mod);
  ln_mod_bf16<<<dim3(M), 256, 0, stream>>>(x, n1g, n1b, mod, 0, 1024, tokb);

  wcast_all<<<dim3(12288), 256, 0, stream>>>(
      Wq, Wk, Wv, Wo, W1, W2, Wqkvt, Wot, W1t, W2t);

  // fused QKV -> q,k,v row-major bf16
  mfma_gemm<<<dim3(24, 32), 256, 0, stream>>>(
      tokb, Wqkvt, M, 3 * CDIM, CDIM, qb, kb, vrow, 0);

  rope_qk<<<dim3(M, 2), 256, 0, stream>>>(qb, kb, kpack, 0.125f * LOG2E);

  vtrans_pack<<<dim3(NN / 64, BB * HEADS), 256, 0, stream>>>(vrow, vpack);

  fattn_pack<<<dim3((NN / 64) * BB * HEADS), 256, 0, stream>>>(
      qb, kpack, vpack, tokb);

  // x1 = x + gate_msa * (attn @ Wo)
  mfma_gemm64<<<dim3(CDIM / 128, M / 64), 256, 0, stream>>>(
      tokb, Wot, M, CDIM, CDIM, x1, x, mod, 2048);

  ln_mod_bf16<<<dim3(M), 256, 0, stream>>>(x1, n2g, n2b, mod, 3072, 4096, tokb);

  // h1 = gelu(xn2 @ W1)
  mfma_gemm<<<dim3(MLPD / 128, M / 128), 256, 0, stream>>>(
      tokb, W1t, M, MLPD, CDIM, h1b, nullptr, nullptr, 1);

  // out = x1 + gate_mlp * (h1 @ W2)
  mfma_gemm64<<<dim3(CDIM / 128, M / 64), 256, 0, stream>>>(
      h1b, W2t, M, CDIM, MLPD, out, x1, mod, 5120);
}